// Round 7
// baseline (288.221 us; speedup 1.0000x reference)
//
#include <hip/hip_runtime.h>
#include <math.h>

#define B 16
#define K 128
#define S 64
#define L 2
#define D 256
#define A 500

#define ROW4_TREES 4096            // 16384 floats / 4 (64 KB)
#define HALF4_HID  4160            // half of a 130 KB hiddens/cells row

// Sentinel for masked beams: far below any N(0,1) score, and FINITE after a
// bf16 round-trip (-FLT_MAX rounds to bf16 -inf -> NaN in harness absmax).
#define NEG_BIG (-1.0e30f)

typedef float f32x4 __attribute__((ext_vector_type(4)));
typedef int   i32x4 __attribute__((ext_vector_type(4)));

// d_out float offsets (concatenated return tuple, all float32)
#define OFF_GENLL 0
#define OFF_TREES 2048
#define OFF_HID   33556480
#define OFF_CELLS 101713920
#define OFF_MARG  169871360
#define OFF_ACT   169871376
#define OFF_APOS  170895376
#define OFF_PTR   170897424
#define OFF_PREV  170899472
#define OFF_NBW   170901520

// Persistent blocks: 2048 = 8 blocks/CU x 256 CUs. Big units: trees rows
// (2048) + hiddens half-rows (4096) + cells half-rows (4096) = 10240 = 5/block.
#define NBLK 2048
#define NU_TREES 2048
#define UPB 5

template<int N4>
__device__ __forceinline__ void copy_unit(const f32x4* __restrict__ s,
                                          f32x4* __restrict__ d, int tid)
{
    constexpr int FULL = N4 / 256;   // 16
    constexpr int REM  = N4 % 256;   // 0 (trees) or 64 (hid/cells half)
    for (int g = 0; g < FULL; g += 8) {
        f32x4 v[8];
#pragma unroll
        for (int i = 0; i < 8; ++i)
            v[i] = __builtin_nontemporal_load(&s[(g + i) * 256 + tid]);
#pragma unroll
        for (int i = 0; i < 8; ++i)
            __builtin_nontemporal_store(v[i], &d[(g + i) * 256 + tid]);
    }
    if (REM && tid < REM) {
        f32x4 v = __builtin_nontemporal_load(&s[FULL * 256 + tid]);
        __builtin_nontemporal_store(v, &d[FULL * 256 + tid]);
    }
}

__global__ void __launch_bounds__(256, 8)
k_fused(const float* __restrict__ gen_ll,
        const f32x4* __restrict__ trees,
        const f32x4* __restrict__ hiddens,
        const f32x4* __restrict__ cells,
        const int* __restrict__ actions,
        const int* __restrict__ actions_pos,
        const int* __restrict__ pointer,
        const int* __restrict__ beam_widths,
        float* __restrict__ out)
{
    __shared__ float key[B][K];      // 8 KB
    __shared__ int   sidx[B][K];     // 8 KB
    __shared__ int   wbuf[B];
    __shared__ float red[4];

    const int tid = threadIdx.x;
    const int bid = blockIdx.x;

    // --- sort ALL 16 batch rows once per block (amortized over block life) ---
    if (tid < B) wbuf[tid] = beam_widths[tid];
    __syncthreads();
    for (int t = tid; t < B * K; t += 256) {
        const int b = t >> 7, i = t & 127;
        key[b][i] = (i < wbuf[b]) ? gen_ll[t] : NEG_BIG;
    }
    __syncthreads();
    for (int t = tid; t < B * K; t += 256) {
        const int b = t >> 7, i = t & 127;
        const float my = key[b][i];
        int rank = 0;
#pragma unroll 16
        for (int ii = 0; ii < K; ++ii) {
            const float ki = key[b][ii];          // wave-broadcast read
            rank += (ki > my) || (ki == my && ii < i);
        }
        sidx[b][rank] = i;                         // stable permutation
    }
    __syncthreads();

    // --- 5 contiguous big 64KB units per block (perfect balance) ---
    const int u0 = bid * UPB;
#pragma unroll
    for (int q = 0; q < UPB; ++q) {
        const int u = u0 + q;
        if (u < NU_TREES) {
            const int b = u >> 7, k = u & 127;
            const int j = sidx[b][k];
            copy_unit<ROW4_TREES>(trees + (size_t)(b * K + j) * ROW4_TREES,
                                  (f32x4*)(out + OFF_TREES) + (size_t)u * ROW4_TREES,
                                  tid);
        } else {
            const int u2 = u - NU_TREES;           // [0, 8192)
            const int which = u2 >> 12;            // 0 = hiddens, 1 = cells
            const int u3 = u2 & 4095;              // 2*row + half
            const int row = u3 >> 1, half = u3 & 1;
            const int b = row >> 7, k = row & 127;
            const int j = sidx[b][k];
            const f32x4* src = (which ? cells : hiddens)
                             + ((size_t)(b * K + j) * 2 + half) * HALF4_HID;
            f32x4* dst = (f32x4*)(out + (which ? OFF_CELLS : OFF_HID))
                       + (size_t)u3 * HALF4_HID;
            copy_unit<HALF4_HID>(src, dst, tid);
        }
    }

    // --- one actions row per block (500 ints = 125 int4, 16B-aligned rows) ---
    {
        const int b = bid >> 7, k = bid & 127;
        const int j = sidx[b][k];
        const i32x4* s = (const i32x4*)actions + (size_t)(b * K + j) * 125;
        f32x4* d = (f32x4*)(out + OFF_ACT) + (size_t)bid * 125;
        if (tid < 125) {
            const i32x4 v = __builtin_nontemporal_load(&s[tid]);
            f32x4 f;
            f.x = (float)v.x; f.y = (float)v.y; f.z = (float)v.z; f.w = (float)v.w;
            __builtin_nontemporal_store(f, &d[tid]);
        }
    }

    // --- small outputs: blocks 0..15 (one batch each) ---
    if (bid < B) {
        const int b = bid;
        if (tid < K) {
            const int j = sidx[b][tid];
            out[OFF_GENLL + b * K + tid] = key[b][j];
            const int ap = actions_pos[b * K + j];
            out[OFF_APOS + b * K + tid] = (float)ap;
            out[OFF_PTR  + b * K + tid] = (float)pointer[b * K + j];
            out[OFF_PREV + b * K + tid] = (float)actions[(size_t)(b * K + j) * A + ap];
        }
        const float v = (tid < K) ? key[b][tid] : NEG_BIG;
        if (tid < 128) {
            float m = v;
#pragma unroll
            for (int mask = 32; mask >= 1; mask >>= 1)
                m = fmaxf(m, __shfl_xor(m, mask, 64));
            if ((tid & 63) == 0) red[tid >> 6] = m;
        }
        __syncthreads();
        const float m = fmaxf(red[0], red[1]);
        if (tid < 128) {
            float e = expf(v - m);                 // masked lanes -> exactly 0
#pragma unroll
            for (int mask = 32; mask >= 1; mask >>= 1)
                e += __shfl_xor(e, mask, 64);
            if ((tid & 63) == 0) red[2 + (tid >> 6)] = e;
        }
        __syncthreads();
        if (tid == 0) {
            out[OFF_MARG + b] = m + logf(red[2] + red[3]);
            const int w = wbuf[b];
            out[OFF_NBW + b] = (float)(w < K ? w : K);
        }
    }
}

extern "C" void kernel_launch(void* const* d_in, const int* in_sizes, int n_in,
                              void* d_out, int out_size, void* d_ws, size_t ws_size,
                              hipStream_t stream)
{
    const float* gen_ll      = (const float*)d_in[0];
    const float* trees       = (const float*)d_in[1];
    const float* hiddens     = (const float*)d_in[2];
    const float* cells       = (const float*)d_in[3];
    const int*   actions     = (const int*)d_in[4];
    const int*   actions_pos = (const int*)d_in[5];
    const int*   pointer     = (const int*)d_in[6];
    const int*   beam_widths = (const int*)d_in[7];
    float* out = (float*)d_out;

    k_fused<<<NBLK, 256, 0, stream>>>(gen_ll, (const f32x4*)trees,
                                      (const f32x4*)hiddens, (const f32x4*)cells,
                                      actions, actions_pos, pointer, beam_widths, out);
}

// Round 8
// 272.335 us; speedup vs baseline: 1.0583x; 1.0583x over previous
//
#include <hip/hip_runtime.h>
#include <math.h>

#define B 16
#define K 128
#define S 64
#define L 2
#define D 256
#define A 500

#define ROW4_TREES 4096            // 16384 floats / 4 (64 KB)
#define HALF4_HID  4160            // half of a 130 KB hiddens/cells row

// Sentinel for masked beams: far below any N(0,1) score, and FINITE after a
// bf16 round-trip (-FLT_MAX rounds to bf16 -inf -> NaN in harness absmax).
#define NEG_BIG (-1.0e30f)

typedef float f32x4 __attribute__((ext_vector_type(4)));
typedef int   i32x4 __attribute__((ext_vector_type(4)));

// d_out float offsets (concatenated return tuple, all float32)
#define OFF_GENLL 0
#define OFF_TREES 2048
#define OFF_HID   33556480
#define OFF_CELLS 101713920
#define OFF_MARG  169871360
#define OFF_ACT   169871376
#define OFF_APOS  170895376
#define OFF_PTR   170897424
#define OFF_PREV  170899472
#define OFF_NBW   170901520

// k_copy: 2048 persistent blocks (8/CU x 256 CU). Big units: trees rows
// (2048) + hiddens half-rows (4096) + cells half-rows (4096) = 10240 = 5/blk.
#define NBLK 2048
#define NU_TREES 2048
#define UPB 5

template<int N4>
__device__ __forceinline__ void copy_unit(const f32x4* __restrict__ s,
                                          f32x4* __restrict__ d, int tid)
{
    constexpr int FULL = N4 / 256;   // 16
    constexpr int REM  = N4 % 256;   // 0 (trees) or 64 (hid/cells half)
    for (int g = 0; g < FULL; g += 8) {
        f32x4 v[8];
#pragma unroll
        for (int i = 0; i < 8; ++i)
            v[i] = __builtin_nontemporal_load(&s[(g + i) * 256 + tid]);
#pragma unroll
        for (int i = 0; i < 8; ++i)
            __builtin_nontemporal_store(v[i], &d[(g + i) * 256 + tid]);
    }
    if (REM && tid < REM) {
        f32x4 v = __builtin_nontemporal_load(&s[FULL * 256 + tid]);
        __builtin_nontemporal_store(v, &d[FULL * 256 + tid]);
    }
}

// ---------------------------------------------------------------------------
// Kernel 1 (tiny, 16 blocks x 128 thr): stable descending rank-sort per batch,
// sidx -> d_ws, plus ALL small outputs (gen_ll_s/apos/ptr/prev/marginal/nbw).
// ---------------------------------------------------------------------------
__global__ void __launch_bounds__(128)
k_sort(const float* __restrict__ gen_ll,
       const int* __restrict__ actions,
       const int* __restrict__ actions_pos,
       const int* __restrict__ pointer,
       const int* __restrict__ beam_widths,
       float* __restrict__ out,
       int* __restrict__ sort_idx)
{
    const int b = blockIdx.x;
    const int k = threadIdx.x;

    __shared__ float key[K];
    __shared__ int   sidx[K];
    __shared__ float red[4];

    const int w = beam_widths[b];
    const float my = (k < w) ? gen_ll[b * K + k] : NEG_BIG;
    key[k] = my;
    __syncthreads();

    int rank = 0;
#pragma unroll 16
    for (int i = 0; i < K; ++i) {
        const float ki = key[i];
        rank += (ki > my) || (ki == my && i < k);
    }
    sidx[rank] = k;                  // stable permutation (tie-break by index)
    __syncthreads();

    const int j = sidx[k];
    sort_idx[b * K + k] = j;

    out[OFF_GENLL + b * K + k] = key[j];
    const int ap = actions_pos[b * K + j];
    out[OFF_APOS + b * K + k] = (float)ap;
    out[OFF_PTR  + b * K + k] = (float)pointer[b * K + j];
    out[OFF_PREV + b * K + k] = (float)actions[(size_t)(b * K + j) * A + ap];

    // parallel logsumexp (2 waves)
    float m = my;
#pragma unroll
    for (int mask = 32; mask >= 1; mask >>= 1)
        m = fmaxf(m, __shfl_xor(m, mask, 64));
    if ((k & 63) == 0) red[k >> 6] = m;
    __syncthreads();
    m = fmaxf(red[0], red[1]);
    float e = expf(my - m);          // masked lanes underflow to exactly 0
#pragma unroll
    for (int mask = 32; mask >= 1; mask >>= 1)
        e += __shfl_xor(e, mask, 64);
    if ((k & 63) == 0) red[2 + (k >> 6)] = e;
    __syncthreads();
    if (k == 0) {
        out[OFF_MARG + b] = m + logf(red[2] + red[3]);
        out[OFF_NBW + b] = (float)(w < K ? w : K);
    }
}

// ---------------------------------------------------------------------------
// Kernel 2: persistent copy blocks. 5 big 64KB units + 1 actions row each.
// j comes from a uniform scalar load of sort_idx (K$-cached) -> zero prelude.
// ---------------------------------------------------------------------------
__global__ void __launch_bounds__(256, 8)
k_copy(const f32x4* __restrict__ trees,
       const f32x4* __restrict__ hiddens,
       const f32x4* __restrict__ cells,
       const int* __restrict__ actions,
       const int* __restrict__ sort_idx,
       float* __restrict__ out)
{
    const int tid = threadIdx.x;
    const int bid = blockIdx.x;

    const int u0 = bid * UPB;
#pragma unroll
    for (int q = 0; q < UPB; ++q) {
        const int u = u0 + q;
        if (u < NU_TREES) {
            const int b = u >> 7, k = u & 127;
            const int j = sort_idx[(b << 7) + k];              // uniform s_load
            copy_unit<ROW4_TREES>(trees + (size_t)(b * K + j) * ROW4_TREES,
                                  (f32x4*)(out + OFF_TREES) + (size_t)u * ROW4_TREES,
                                  tid);
        } else {
            const int u2 = u - NU_TREES;          // [0, 8192)
            const int which = u2 >> 12;           // 0 = hiddens, 1 = cells
            const int u3 = u2 & 4095;             // 2*row + half
            const int row = u3 >> 1, half = u3 & 1;
            const int b = row >> 7, k = row & 127;
            const int j = sort_idx[(b << 7) + k];              // uniform s_load
            const f32x4* src = (which ? cells : hiddens)
                             + ((size_t)(b * K + j) * 2 + half) * HALF4_HID;
            f32x4* dst = (f32x4*)(out + (which ? OFF_CELLS : OFF_HID))
                       + (size_t)u3 * HALF4_HID;
            copy_unit<HALF4_HID>(src, dst, tid);
        }
    }

    // one actions row per block (500 ints = 125 int4; 2000 B rows, 16B-aligned)
    {
        const int b = bid >> 7;
        const int j = sort_idx[bid];                           // uniform s_load
        const i32x4* s = (const i32x4*)actions + (size_t)(b * K + j) * 125;
        f32x4* d = (f32x4*)(out + OFF_ACT) + (size_t)bid * 125;
        if (tid < 125) {
            const i32x4 v = __builtin_nontemporal_load(&s[tid]);
            f32x4 f;
            f.x = (float)v.x; f.y = (float)v.y; f.z = (float)v.z; f.w = (float)v.w;
            __builtin_nontemporal_store(f, &d[tid]);
        }
    }
}

extern "C" void kernel_launch(void* const* d_in, const int* in_sizes, int n_in,
                              void* d_out, int out_size, void* d_ws, size_t ws_size,
                              hipStream_t stream)
{
    const float* gen_ll      = (const float*)d_in[0];
    const float* trees       = (const float*)d_in[1];
    const float* hiddens     = (const float*)d_in[2];
    const float* cells       = (const float*)d_in[3];
    const int*   actions     = (const int*)d_in[4];
    const int*   actions_pos = (const int*)d_in[5];
    const int*   pointer     = (const int*)d_in[6];
    const int*   beam_widths = (const int*)d_in[7];
    float* out = (float*)d_out;
    int* sort_idx = (int*)d_ws;

    k_sort<<<B, K, 0, stream>>>(gen_ll, actions, actions_pos, pointer,
                                beam_widths, out, sort_idx);
    k_copy<<<NBLK, 256, 0, stream>>>((const f32x4*)trees, (const f32x4*)hiddens,
                                     (const f32x4*)cells, actions, sort_idx, out);
}

// Round 9
// 268.359 us; speedup vs baseline: 1.0740x; 1.0148x over previous
//
#include <hip/hip_runtime.h>
#include <math.h>

#define B 16
#define K 128
#define S 64
#define L 2
#define D 256
#define A 500

// Sentinel for masked beams: far below any N(0,1) score, and FINITE after a
// bf16 round-trip (-FLT_MAX rounds to bf16 -inf -> NaN in harness absmax).
#define NEG_BIG (-1.0e30f)

typedef float f32x4 __attribute__((ext_vector_type(4)));
typedef int   i32x4 __attribute__((ext_vector_type(4)));

// d_out float offsets (concatenated return tuple, all float32)
#define OFF_GENLL 0
#define OFF_TREES 2048
#define OFF_HID   33556480
#define OFF_CELLS 101713920
#define OFF_MARG  169871360
#define OFF_ACT   169871376
#define OFF_APOS  170895376
#define OFF_PTR   170897424
#define OFF_PREV  170899472
#define OFF_NBW   170901520

// region geometry in f32x4 (16B) units
#define ROW4_T 4096                 // trees row
#define ROW4_H 8320                 // hiddens/cells row
#define AROW4  125                  // actions row (500 ints)
#define N4_T   (2048 * ROW4_T)      // 8,388,608
#define N4_H   (2048 * ROW4_H)      // 17,039,360
#define N4_A   (2048 * AROW4)       // 256,000

// block partition of the 2048-block resident grid (8 blocks/CU x 256 CU),
// proportional to region bytes -> ~82 grid-stride iters/thread everywhere.
#define NB_T 398
#define NB_H 809
#define NB_C 809
#define NB_A 32
#define NBLK (NB_T + NB_H + NB_C + NB_A)   // 2048

// ---------------------------------------------------------------------------
// Kernel 1 (16 blocks x 128 thr): stable descending rank-sort per batch.
// Writes srcrow[r] = b*K + j (absolute source row) to d_ws and ALL small
// outputs (gen_ll_s / apos / ptr / prev / marginal / nbw).
// ---------------------------------------------------------------------------
__global__ void __launch_bounds__(128)
k_sort(const float* __restrict__ gen_ll,
       const int* __restrict__ actions,
       const int* __restrict__ actions_pos,
       const int* __restrict__ pointer,
       const int* __restrict__ beam_widths,
       float* __restrict__ out,
       int* __restrict__ srcrow)
{
    const int b = blockIdx.x;
    const int k = threadIdx.x;

    __shared__ float key[K];
    __shared__ int   sidx[K];
    __shared__ float red[4];

    const int w = beam_widths[b];
    const float my = (k < w) ? gen_ll[b * K + k] : NEG_BIG;
    key[k] = my;
    __syncthreads();

    int rank = 0;
#pragma unroll 16
    for (int i = 0; i < K; ++i) {
        const float ki = key[i];
        rank += (ki > my) || (ki == my && i < k);
    }
    sidx[rank] = k;                  // stable permutation (tie-break by index)
    __syncthreads();

    const int j = sidx[k];
    srcrow[b * K + k] = b * K + j;

    out[OFF_GENLL + b * K + k] = key[j];
    const int ap = actions_pos[b * K + j];
    out[OFF_APOS + b * K + k] = (float)ap;
    out[OFF_PTR  + b * K + k] = (float)pointer[b * K + j];
    out[OFF_PREV + b * K + k] = (float)actions[(size_t)(b * K + j) * A + ap];

    // parallel logsumexp (2 waves)
    float m = my;
#pragma unroll
    for (int mask = 32; mask >= 1; mask >>= 1)
        m = fmaxf(m, __shfl_xor(m, mask, 64));
    if ((k & 63) == 0) red[k >> 6] = m;
    __syncthreads();
    m = fmaxf(red[0], red[1]);
    float e = expf(my - m);          // masked lanes underflow to exactly 0
#pragma unroll
    for (int mask = 32; mask >= 1; mask >>= 1)
        e += __shfl_xor(e, mask, 64);
    if ((k & 63) == 0) red[2 + (k >> 6)] = e;
    __syncthreads();
    if (k == 0) {
        out[OFF_MARG + b] = m + logf(red[2] + red[3]);
        out[OFF_NBW + b] = (float)(w < K ? w : K);
    }
}

// flat gather copy: dst[i] = src[srcrow[i/ROW]*ROW + i%ROW], 4x unrolled
template<int ROW4, bool POW2>
__device__ __forceinline__ void region_copy(const f32x4* __restrict__ src,
                                            f32x4* __restrict__ dst,
                                            const int* __restrict__ srcrow,
                                            int start, int stride, int n4)
{
    int i = start;
    for (; i + 3 * stride < n4; i += 4 * stride) {
        const int i0 = i, i1 = i + stride, i2 = i + 2 * stride, i3 = i + 3 * stride;
        int r0, r1, r2, r3, o0, o1, o2, o3;
        if (POW2) {
            r0 = i0 >> 12; o0 = i0 & (ROW4 - 1);
            r1 = i1 >> 12; o1 = i1 & (ROW4 - 1);
            r2 = i2 >> 12; o2 = i2 & (ROW4 - 1);
            r3 = i3 >> 12; o3 = i3 & (ROW4 - 1);
        } else {
            r0 = i0 / ROW4; o0 = i0 - r0 * ROW4;
            r1 = i1 / ROW4; o1 = i1 - r1 * ROW4;
            r2 = i2 / ROW4; o2 = i2 - r2 * ROW4;
            r3 = i3 / ROW4; o3 = i3 - r3 * ROW4;
        }
        const f32x4 v0 = __builtin_nontemporal_load(&src[(size_t)srcrow[r0] * ROW4 + o0]);
        const f32x4 v1 = __builtin_nontemporal_load(&src[(size_t)srcrow[r1] * ROW4 + o1]);
        const f32x4 v2 = __builtin_nontemporal_load(&src[(size_t)srcrow[r2] * ROW4 + o2]);
        const f32x4 v3 = __builtin_nontemporal_load(&src[(size_t)srcrow[r3] * ROW4 + o3]);
        __builtin_nontemporal_store(v0, &dst[i0]);
        __builtin_nontemporal_store(v1, &dst[i1]);
        __builtin_nontemporal_store(v2, &dst[i2]);
        __builtin_nontemporal_store(v3, &dst[i3]);
    }
    for (; i < n4; i += stride) {
        const int r = POW2 ? (i >> 12) : (i / ROW4);
        const int o = POW2 ? (i & (ROW4 - 1)) : (i - r * ROW4);
        const f32x4 v = __builtin_nontemporal_load(&src[(size_t)srcrow[r] * ROW4 + o]);
        __builtin_nontemporal_store(v, &dst[i]);
    }
}

// ---------------------------------------------------------------------------
// Kernel 2: fill-style flat grid-stride gather. 2048 blocks = 8/CU resident,
// partitioned into 4 independent region groups. No LDS, no barriers.
// ---------------------------------------------------------------------------
__global__ void __launch_bounds__(256, 8)
k_copy(const f32x4* __restrict__ trees,
       const f32x4* __restrict__ hiddens,
       const f32x4* __restrict__ cells,
       const i32x4* __restrict__ actions,
       const int* __restrict__ srcrow,
       float* __restrict__ out)
{
    const int tid = threadIdx.x;
    const int bid = blockIdx.x;

    if (bid < NB_T) {
        region_copy<ROW4_T, true>(trees, (f32x4*)(out + OFF_TREES), srcrow,
                                  bid * 256 + tid, NB_T * 256, N4_T);
    } else if (bid < NB_T + NB_H) {
        region_copy<ROW4_H, false>(hiddens, (f32x4*)(out + OFF_HID), srcrow,
                                   (bid - NB_T) * 256 + tid, NB_H * 256, N4_H);
    } else if (bid < NB_T + NB_H + NB_C) {
        region_copy<ROW4_H, false>(cells, (f32x4*)(out + OFF_CELLS), srcrow,
                                   (bid - NB_T - NB_H) * 256 + tid, NB_C * 256, N4_H);
    } else {
        // actions: int4 -> float4 convert, same flat pattern
        f32x4* dst = (f32x4*)(out + OFF_ACT);
        const int start = (bid - NB_T - NB_H - NB_C) * 256 + tid;
        const int stride = NB_A * 256;
        for (int i = start; i < N4_A; i += stride) {
            const int r = i / AROW4;
            const int o = i - r * AROW4;
            const i32x4 v = __builtin_nontemporal_load(&actions[(size_t)srcrow[r] * AROW4 + o]);
            f32x4 f;
            f.x = (float)v.x; f.y = (float)v.y; f.z = (float)v.z; f.w = (float)v.w;
            __builtin_nontemporal_store(f, &dst[i]);
        }
    }
}

extern "C" void kernel_launch(void* const* d_in, const int* in_sizes, int n_in,
                              void* d_out, int out_size, void* d_ws, size_t ws_size,
                              hipStream_t stream)
{
    const float* gen_ll      = (const float*)d_in[0];
    const float* trees       = (const float*)d_in[1];
    const float* hiddens     = (const float*)d_in[2];
    const float* cells       = (const float*)d_in[3];
    const int*   actions     = (const int*)d_in[4];
    const int*   actions_pos = (const int*)d_in[5];
    const int*   pointer     = (const int*)d_in[6];
    const int*   beam_widths = (const int*)d_in[7];
    float* out = (float*)d_out;
    int* srcrow = (int*)d_ws;

    k_sort<<<B, K, 0, stream>>>(gen_ll, actions, actions_pos, pointer,
                                beam_widths, out, srcrow);
    k_copy<<<NBLK, 256, 0, stream>>>((const f32x4*)trees, (const f32x4*)hiddens,
                                     (const f32x4*)cells, (const i32x4*)actions,
                                     srcrow, out);
}

// Round 10
// 256.004 us; speedup vs baseline: 1.1258x; 1.0483x over previous
//
#include <hip/hip_runtime.h>
#include <math.h>

#define B 16
#define K 128
#define S 64
#define L 2
#define D 256
#define A 500

#define ROW4_TREES 4096            // 16384 floats / 4 (64 KB)
#define HALF4_HID  4160            // half of a 130 KB hiddens/cells row

// Sentinel for masked beams: far below any N(0,1) score, and FINITE after a
// bf16 round-trip (-FLT_MAX rounds to bf16 -inf -> NaN in harness absmax).
#define NEG_BIG (-1.0e30f)

typedef float f32x4 __attribute__((ext_vector_type(4)));
typedef int   i32x4 __attribute__((ext_vector_type(4)));

// d_out float offsets (concatenated return tuple, all float32)
#define OFF_GENLL 0
#define OFF_TREES 2048
#define OFF_HID   33556480
#define OFF_CELLS 101713920
#define OFF_MARG  169871360
#define OFF_ACT   169871376
#define OFF_APOS  170895376
#define OFF_PTR   170897424
#define OFF_PREV  170899472
#define OFF_NBW   170901520

// Uniform grid: 2048 trees blocks (each also carries its actions row; the
// first 16 also emit the small outputs), then 8192 hid/cells half-row blocks.
#define NU_TREES 2048
#define GRID (NU_TREES + 8192)     // 10240 blocks, one 64KB unit each

template<int N4>
__device__ __forceinline__ void copy_unit(const f32x4* __restrict__ s,
                                          f32x4* __restrict__ d, int tid)
{
    constexpr int FULL = N4 / 256;   // 16
    constexpr int REM  = N4 % 256;   // 0 (trees) or 64 (hid/cells half)
    for (int g = 0; g < FULL; g += 8) {
        f32x4 v[8];
#pragma unroll
        for (int i = 0; i < 8; ++i)
            v[i] = __builtin_nontemporal_load(&s[(g + i) * 256 + tid]);
#pragma unroll
        for (int i = 0; i < 8; ++i)
            __builtin_nontemporal_store(v[i], &d[(g + i) * 256 + tid]);
    }
    if (REM && tid < REM) {
        f32x4 v = __builtin_nontemporal_load(&s[FULL * 256 + tid]);
        __builtin_nontemporal_store(v, &d[FULL * 256 + tid]);
    }
}

__global__ void __launch_bounds__(256, 8)
k_fused(const float* __restrict__ gen_ll,
        const f32x4* __restrict__ trees,
        const f32x4* __restrict__ hiddens,
        const f32x4* __restrict__ cells,
        const int* __restrict__ actions,
        const int* __restrict__ actions_pos,
        const int* __restrict__ pointer,
        const int* __restrict__ beam_widths,
        float* __restrict__ out)
{
    __shared__ float key[K];
    __shared__ int   sidx[K];
    __shared__ float red[4];

    const int tid = threadIdx.x;
    const int bid = blockIdx.x;

    // decode work item
    int b, k;
    int which = -1, u3 = 0;          // which: -1 trees, 0 hiddens, 1 cells
    if (bid < NU_TREES) {
        b = bid >> 7; k = bid & 127;
    } else {
        const int u2 = bid - NU_TREES;            // [0, 8192)
        which = u2 >> 12;                          // 0 = hiddens, 1 = cells
        u3 = u2 & 4095;                            // 2*row + half
        const int row = u3 >> 1;
        b = row >> 7; k = row & 127;
    }

    // --- stable descending rank-sort of batch row b (hidden under copies) ---
    const int w = beam_widths[b];
    if (tid < K) key[tid] = (tid < w) ? gen_ll[b * K + tid] : NEG_BIG;
    __syncthreads();
    if (tid < K) {
        const float my = key[tid];
        int rank = 0;
#pragma unroll 16
        for (int i = 0; i < K; ++i) {
            const float ki = key[i];               // wave-broadcast LDS read
            rank += (ki > my) || (ki == my && i < tid);
        }
        sidx[rank] = tid;            // stable permutation (tie-break by index)
    }
    __syncthreads();

    const int j = sidx[k];           // source beam for this block's row

    if (which < 0) {
        // trees unit
        copy_unit<ROW4_TREES>(trees + (size_t)(b * K + j) * ROW4_TREES,
                              (f32x4*)(out + OFF_TREES) + (size_t)bid * ROW4_TREES,
                              tid);
        // piggyback: actions row bid (same (b,k) -> same j). 500 ints = 125 int4.
        {
            const i32x4* s = (const i32x4*)actions + (size_t)(b * K + j) * 125;
            f32x4* d = (f32x4*)(out + OFF_ACT) + (size_t)bid * 125;
            if (tid < 125) {
                const i32x4 v = __builtin_nontemporal_load(&s[tid]);
                f32x4 f;
                f.x = (float)v.x; f.y = (float)v.y; f.z = (float)v.z; f.w = (float)v.w;
                __builtin_nontemporal_store(f, &d[tid]);
            }
        }
        // piggyback: small outputs on blocks 0..15 (k==... block bid<16 -> b=0,
        // k=bid; need one block per BATCH: use blocks with k==0, i.e. bid%128==0?
        // No: blocks 0..15 all have b=0. Use bid = b*128 (k==0) instead.
        if (k == 0) {
            // this block handles batch b's small outputs
            if (tid < K) {
                const int jj = sidx[tid];
                out[OFF_GENLL + b * K + tid] = key[jj];
                const int ap = actions_pos[b * K + jj];
                out[OFF_APOS + b * K + tid] = (float)ap;
                out[OFF_PTR  + b * K + tid] = (float)pointer[b * K + jj];
                out[OFF_PREV + b * K + tid] = (float)actions[(size_t)(b * K + jj) * A + ap];
            }
            const float v = (tid < K) ? key[tid] : NEG_BIG;
            if (tid < 128) {
                float m = v;
#pragma unroll
                for (int mask = 32; mask >= 1; mask >>= 1)
                    m = fmaxf(m, __shfl_xor(m, mask, 64));
                if ((tid & 63) == 0) red[tid >> 6] = m;
            }
            __syncthreads();
            const float m = fmaxf(red[0], red[1]);
            if (tid < 128) {
                float e = expf(v - m);             // masked lanes -> exactly 0
#pragma unroll
                for (int mask = 32; mask >= 1; mask >>= 1)
                    e += __shfl_xor(e, mask, 64);
                if ((tid & 63) == 0) red[2 + (tid >> 6)] = e;
            }
            __syncthreads();
            if (tid == 0) {
                out[OFF_MARG + b] = m + logf(red[2] + red[3]);
                out[OFF_NBW + b] = (float)(w < K ? w : K);
            }
        }
    } else {
        const int half = u3 & 1;
        const f32x4* src = (which ? cells : hiddens)
                         + ((size_t)(b * K + j) * 2 + half) * HALF4_HID;
        f32x4* dst = (f32x4*)(out + (which ? OFF_CELLS : OFF_HID))
                   + (size_t)u3 * HALF4_HID;
        copy_unit<HALF4_HID>(src, dst, tid);
    }
}

extern "C" void kernel_launch(void* const* d_in, const int* in_sizes, int n_in,
                              void* d_out, int out_size, void* d_ws, size_t ws_size,
                              hipStream_t stream)
{
    const float* gen_ll      = (const float*)d_in[0];
    const float* trees       = (const float*)d_in[1];
    const float* hiddens     = (const float*)d_in[2];
    const float* cells       = (const float*)d_in[3];
    const int*   actions     = (const int*)d_in[4];
    const int*   actions_pos = (const int*)d_in[5];
    const int*   pointer     = (const int*)d_in[6];
    const int*   beam_widths = (const int*)d_in[7];
    float* out = (float*)d_out;

    k_fused<<<GRID, 256, 0, stream>>>(gen_ll, (const f32x4*)trees,
                                      (const f32x4*)hiddens, (const f32x4*)cells,
                                      actions, actions_pos, pointer, beam_widths, out);
}

// Round 11
// 252.785 us; speedup vs baseline: 1.1402x; 1.0127x over previous
//
#include <hip/hip_runtime.h>
#include <math.h>

#define B 16
#define K 128
#define S 64
#define L 2
#define D 256
#define A 500

#define ROW4_TREES 4096            // 16384 floats / 4 (64 KB)
#define HALF4_HID  4160            // half of a 130 KB hiddens/cells row

// Sentinel for masked beams: far below any N(0,1) score, and FINITE after a
// bf16 round-trip (-FLT_MAX rounds to bf16 -inf -> NaN in harness absmax).
#define NEG_BIG (-1.0e30f)

typedef float f32x4 __attribute__((ext_vector_type(4)));
typedef int   i32x4 __attribute__((ext_vector_type(4)));

// d_out float offsets (concatenated return tuple, all float32)
#define OFF_GENLL 0
#define OFF_TREES 2048
#define OFF_HID   33556480
#define OFF_CELLS 101713920
#define OFF_MARG  169871360
#define OFF_ACT   169871376
#define OFF_APOS  170895376
#define OFF_PTR   170897424
#define OFF_PREV  170899472
#define OFF_NBW   170901520

// Uniform grid: 2048 trees blocks (each also scatters its actions row; the
// k==0 blocks emit the small outputs), then 8192 hid/cells half-row blocks.
// SCATTER form: block (b,k) READS source row (b,k) contiguously (address
// known immediately -> payload loads issue before the sort), and WRITES to
// output row rank(k). rank is a bijection == inverse of the gather sidx.
#define NU_TREES 2048
#define GRID (NU_TREES + 8192)     // 10240 blocks, one 64KB unit each

__global__ void __launch_bounds__(256, 8)
k_fused(const float* __restrict__ gen_ll,
        const f32x4* __restrict__ trees,
        const f32x4* __restrict__ hiddens,
        const f32x4* __restrict__ cells,
        const int* __restrict__ actions,
        const int* __restrict__ actions_pos,
        const int* __restrict__ pointer,
        const int* __restrict__ beam_widths,
        float* __restrict__ out)
{
    __shared__ float key[K];
    __shared__ int   sidx[K];
    __shared__ int   rnk[K];
    __shared__ float red[4];

    const int tid = threadIdx.x;
    const int bid = blockIdx.x;

    // decode SOURCE work item
    int b, k, which = -1, half = 0;
    if (bid < NU_TREES) {
        b = bid >> 7; k = bid & 127;
    } else {
        const int u2 = bid - NU_TREES;            // [0, 8192)
        which = u2 >> 12;                          // 0 = hiddens, 1 = cells
        const int u3 = u2 & 4095;                  // 2*row + half
        half = u3 & 1;
        const int row = u3 >> 1;
        b = row >> 7; k = row & 127;
    }

    // source pointer is sort-independent: issue first 8-deep load batch NOW
    const f32x4* s = (which < 0)
        ? trees + (size_t)(b * K + k) * ROW4_TREES
        : (which ? cells : hiddens) + ((size_t)(b * K + k) * 2 + half) * HALF4_HID;
    f32x4 v[8];
#pragma unroll
    for (int i = 0; i < 8; ++i)
        v[i] = __builtin_nontemporal_load(&s[i * 256 + tid]);

    // --- stable descending rank-sort of batch row b (overlaps load latency) ---
    const int w = beam_widths[b];
    if (tid < K) key[tid] = (tid < w) ? gen_ll[b * K + tid] : NEG_BIG;
    __syncthreads();
    if (tid < K) {
        const float my = key[tid];
        int rank = 0;
#pragma unroll 16
        for (int i = 0; i < K; ++i) {
            const float ki = key[i];               // wave-broadcast LDS read
            rank += (ki > my) || (ki == my && i < tid);
        }
        sidx[rank] = tid;            // gather permutation (for small outputs)
        rnk[tid] = rank;             // scatter destination of beam tid
    }
    __syncthreads();

    const int rr = rnk[k];           // destination rank-row for this block

    if (which < 0) {
        f32x4* d = (f32x4*)(out + OFF_TREES) + (size_t)((b << 7) + rr) * ROW4_TREES;
#pragma unroll
        for (int i = 0; i < 8; ++i)
            __builtin_nontemporal_store(v[i], &d[i * 256 + tid]);
#pragma unroll
        for (int i = 0; i < 8; ++i)
            v[i] = __builtin_nontemporal_load(&s[(8 + i) * 256 + tid]);
#pragma unroll
        for (int i = 0; i < 8; ++i)
            __builtin_nontemporal_store(v[i], &d[(8 + i) * 256 + tid]);

        // piggyback: actions row (b,k) -> rank row. 500 ints = 125 int4.
        {
            const i32x4* sa = (const i32x4*)actions + (size_t)(b * K + k) * 125;
            f32x4* da = (f32x4*)(out + OFF_ACT) + (size_t)((b << 7) + rr) * 125;
            if (tid < 125) {
                const i32x4 av = __builtin_nontemporal_load(&sa[tid]);
                f32x4 f;
                f.x = (float)av.x; f.y = (float)av.y; f.z = (float)av.z; f.w = (float)av.w;
                __builtin_nontemporal_store(f, &da[tid]);
            }
        }

        // piggyback: small outputs on the k==0 block of each batch (bid = b*128)
        if (k == 0) {
            if (tid < K) {
                const int jj = sidx[tid];
                out[OFF_GENLL + b * K + tid] = key[jj];
                const int ap = actions_pos[b * K + jj];
                out[OFF_APOS + b * K + tid] = (float)ap;
                out[OFF_PTR  + b * K + tid] = (float)pointer[b * K + jj];
                out[OFF_PREV + b * K + tid] = (float)actions[(size_t)(b * K + jj) * A + ap];
            }
            const float vv = (tid < K) ? key[tid] : NEG_BIG;
            if (tid < 128) {
                float m = vv;
#pragma unroll
                for (int mask = 32; mask >= 1; mask >>= 1)
                    m = fmaxf(m, __shfl_xor(m, mask, 64));
                if ((tid & 63) == 0) red[tid >> 6] = m;
            }
            __syncthreads();
            const float m = fmaxf(red[0], red[1]);
            if (tid < 128) {
                float e = expf(vv - m);            // masked lanes -> exactly 0
#pragma unroll
                for (int mask = 32; mask >= 1; mask >>= 1)
                    e += __shfl_xor(e, mask, 64);
                if ((tid & 63) == 0) red[2 + (tid >> 6)] = e;
            }
            __syncthreads();
            if (tid == 0) {
                out[OFF_MARG + b] = m + logf(red[2] + red[3]);
                out[OFF_NBW + b] = (float)(w < K ? w : K);
            }
        }
    } else {
        f32x4* d = (f32x4*)(out + (which ? OFF_CELLS : OFF_HID))
                 + ((size_t)((b << 7) + rr) * 2 + half) * HALF4_HID;
#pragma unroll
        for (int i = 0; i < 8; ++i)
            __builtin_nontemporal_store(v[i], &d[i * 256 + tid]);
#pragma unroll
        for (int i = 0; i < 8; ++i)
            v[i] = __builtin_nontemporal_load(&s[(8 + i) * 256 + tid]);
#pragma unroll
        for (int i = 0; i < 8; ++i)
            __builtin_nontemporal_store(v[i], &d[(8 + i) * 256 + tid]);
        // remainder: 4160 = 16*256 + 64
        if (tid < 64) {
            const f32x4 t = __builtin_nontemporal_load(&s[16 * 256 + tid]);
            __builtin_nontemporal_store(t, &d[16 * 256 + tid]);
        }
    }
}

extern "C" void kernel_launch(void* const* d_in, const int* in_sizes, int n_in,
                              void* d_out, int out_size, void* d_ws, size_t ws_size,
                              hipStream_t stream)
{
    const float* gen_ll      = (const float*)d_in[0];
    const float* trees       = (const float*)d_in[1];
    const float* hiddens     = (const float*)d_in[2];
    const float* cells       = (const float*)d_in[3];
    const int*   actions     = (const int*)d_in[4];
    const int*   actions_pos = (const int*)d_in[5];
    const int*   pointer     = (const int*)d_in[6];
    const int*   beam_widths = (const int*)d_in[7];
    float* out = (float*)d_out;

    k_fused<<<GRID, 256, 0, stream>>>(gen_ll, (const f32x4*)trees,
                                      (const f32x4*)hiddens, (const f32x4*)cells,
                                      actions, actions_pos, pointer, beam_widths, out);
}